// Round 10
// baseline (288.826 us; speedup 1.0000x reference)
//
#include <hip/hip_runtime.h>
#include <hip/hip_bf16.h>
#include <stdint.h>

#define B_ 2
#define Qn 2048
#define Kn 2048
#define Hn 16
#define Dn 128
#define QT 128     // q rows per job (8 waves x 16)
#define KT 64      // keys per tile, pass 2
#define KT1 128    // keys per tile, pass 1
#define HD (Hn*Dn)
#define KROW 132   // K row stride in shorts (264 B)
#define VROW 72    // Vt row stride in shorts (144 B)

typedef __bf16 bf16x8 __attribute__((ext_vector_type(8)));
typedef __bf16 bf16x4 __attribute__((ext_vector_type(4)));
typedef float f32x4 __attribute__((ext_vector_type(4)));

union BF8 { __bf16 e[8]; bf16x8 v; };

#define SCALE 0.088388347648318447f  // 1/sqrt(128)

struct SMp2 { unsigned short K[2][KT][KROW]; unsigned short V[2][Dn][VROW]; };
union SMu { SMp2 p2; unsigned short K1[2][KT1][KROW]; };   // 70.7 KB -> 2 blocks/CU

// lgkm-only barrier: orders LDS ops across the block WITHOUT draining vmcnt
// (attn stores & prefetch loads stay in flight).
__device__ __forceinline__ void bar_lgkm() {
  asm volatile("s_waitcnt lgkmcnt(0)" ::: "memory");
  __builtin_amdgcn_s_barrier();
  __builtin_amdgcn_sched_barrier(0);
}

__device__ __forceinline__ bf16x4 cvt4(f32x4 a) {
  bf16x4 r;
  r[0] = (__bf16)a[0]; r[1] = (__bf16)a[1];
  r[2] = (__bf16)a[2]; r[3] = (__bf16)a[3];
  return r;
}

__device__ __forceinline__ void stage_k64(const float* kb, unsigned short (*dst)[KROW], int tid) {
  #pragma unroll
  for (int ii = 0; ii < 4; ++ii) {
    int chunk = ii * 512 + tid;           // 64 rows x 32 chunks
    int row = chunk >> 5, cv = chunk & 31;
    f32x4 a = *(const f32x4*)(kb + (size_t)row * HD + cv * 4);
    *(bf16x4*)&dst[row][cv * 4] = cvt4(a);
  }
}

__device__ __forceinline__ void stage_k128(const float* kb, unsigned short (*dst)[KROW], int tid) {
  #pragma unroll
  for (int ii = 0; ii < 8; ++ii) {
    int chunk = ii * 512 + tid;           // 128 rows x 32 chunks
    int row = chunk >> 5, cv = chunk & 31;
    f32x4 a = *(const f32x4*)(kb + (size_t)row * HD + cv * 4);
    *(bf16x4*)&dst[row][cv * 4] = cvt4(a);
  }
}

// V^T: chunk (kk,gg) of row d holds keys kk*32 + {4gg..4gg+3, 16+4gg..16+4gg+3}
__device__ __forceinline__ void stage_v64(const float* vb, unsigned short (*dst)[VROW], int tid) {
  int d = tid & 127, t0 = tid >> 7;       // t0 in [0,4)
  const float* colp = vb + d;
  #pragma unroll
  for (int rr = 0; rr < 2; ++rr) {
    int idx = rr * 4 + t0;                // [0,8)
    int kk = idx >> 2, gg = idx & 3;
    int kb0 = kk * 32 + gg * 4;
    BF8 t;
    #pragma unroll
    for (int j = 0; j < 4; ++j) {
      t.e[j]     = (__bf16)colp[(size_t)(kb0 + j) * HD];
      t.e[4 + j] = (__bf16)colp[(size_t)(kb0 + 16 + j) * HD];
    }
    *(bf16x8*)&dst[d][kk * 32 + gg * 8] = t.v;
  }
}

__device__ __forceinline__ void load_q(const float* qrow, BF8* qf, int g) {
  #pragma unroll
  for (int s = 0; s < 4; ++s) {
    f32x4 a0 = *(const f32x4*)(qrow + s * 32 + g * 8);
    f32x4 a1 = *(const f32x4*)(qrow + s * 32 + g * 8 + 4);
    #pragma unroll
    for (int j = 0; j < 4; ++j) { qf[s].e[j] = (__bf16)a0[j]; qf[s].e[4 + j] = (__bf16)a1[j]; }
  }
}

__global__ __launch_bounds__(512, 4) void attn_fwd(
    const float* __restrict__ qs, const float* __restrict__ ks,
    const float* __restrict__ vs, const int* __restrict__ vlen,
    float* __restrict__ ctx_out, float* __restrict__ attn_out)
{
  __shared__ __align__(16) SMu sm;

  const int tid = threadIdx.x, wave = tid >> 6, lane = tid & 63;
  const int c = lane & 15, g = lane >> 4;

  // 256 blocks; each runs one batch-0 job + one batch-1 job (same h, qt).
  // Per-block work = f(vl0) + f(vl1): identical for ALL blocks -> balanced.
  const int L   = blockIdx.x;
  const int xcd = L & 7;
  const int i5  = L >> 3;                  // 0..31
  const int h   = ((i5 & 1) << 3) + xcd;   // 0..15
  const int qt  = i5 >> 1;                 // 0..15

  #pragma unroll 1
  for (int b = 0; b < B_; ++b) {
    if (b) __syncthreads();                // LDS handoff between jobs
    const int bh = b * Hn + h;
    const int vl = vlen[b];
    const int qb = qt * QT + wave * 16;

    BF8 qf[4];
    load_q(qs + (((size_t)(b * Qn + qb + c)) * Hn + h) * Dn, qf, g);
    const float* kbase = ks + ((size_t)b * Kn * Hn + h) * Dn;
    const float* vbase = vs + ((size_t)b * Kn * Hn + h) * Dn;

    // ---------------- pass 1: row sums of exp (KT1=128 tiles) ----------------
    float rs = 0.f;
    {
      const int nkt = (vl + KT1 - 1) / KT1;
      stage_k128(kbase, sm.K1[0], tid);
      bar_lgkm();
      for (int t = 0; t < nkt; ++t) {
        const int cur = t & 1;
        if (t + 1 < nkt) stage_k128(kbase + (size_t)(t + 1) * KT1 * HD, sm.K1[cur ^ 1], tid);
        #pragma unroll
        for (int nt = 0; nt < 8; ++nt) {
          f32x4 acc = {0.f, 0.f, 0.f, 0.f};
          #pragma unroll
          for (int s = 0; s < 4; ++s) {
            BF8 kf; kf.v = *(const bf16x8*)&sm.K1[cur][nt * 16 + c][s * 32 + g * 8];
            acc = __builtin_amdgcn_mfma_f32_16x16x32_bf16(kf.v, qf[s].v, acc, 0, 0, 0);
          }
          const int k0 = t * KT1 + nt * 16 + g * 4;
          #pragma unroll
          for (int r = 0; r < 4; ++r)
            rs += (k0 + r < vl) ? __expf(acc[r] * SCALE) : 0.f;
        }
        bar_lgkm();
      }
    }
    rs += __shfl_xor(rs, 16);
    rs += __shfl_xor(rs, 32);
    const float inv = 1.0f / rs;   // row sum for q-row (qb + c)

    // ---------------- pass 2: attn writes + PV (KT=64 tiles) ----------------
    f32x4 ctxa[8];
    #pragma unroll
    for (int ii = 0; ii < 8; ++ii) ctxa[ii] = (f32x4){0.f, 0.f, 0.f, 0.f};

    const int nkt = (vl + KT - 1) / KT;
    stage_k64(kbase, sm.p2.K[0], tid);
    stage_v64(vbase, sm.p2.V[0], tid);
    bar_lgkm();
    float* rowp = attn_out + ((size_t)bh * Qn + qb + c) * Kn;
    for (int t = 0; t < nkt; ++t) {
      const int cur = t & 1;
      if (t + 1 < nkt) {
        stage_k64(kbase + (size_t)(t + 1) * KT * HD, sm.p2.K[cur ^ 1], tid);
        stage_v64(vbase + (size_t)(t + 1) * KT * HD, sm.p2.V[cur ^ 1], tid);
      }
      // S^T tile: lane (c,g) holds S[q=c][k = t*64 + nt*16 + g*4 + r]
      BF8 pf[2];
      #pragma unroll
      for (int nt = 0; nt < 4; ++nt) {
        f32x4 acc = {0.f, 0.f, 0.f, 0.f};
        #pragma unroll
        for (int s = 0; s < 4; ++s) {
          BF8 kf; kf.v = *(const bf16x8*)&sm.p2.K[cur][nt * 16 + c][s * 32 + g * 8];
          acc = __builtin_amdgcn_mfma_f32_16x16x32_bf16(kf.v, qf[s].v, acc, 0, 0, 0);
        }
        const int k0 = t * KT + nt * 16 + g * 4;
        f32x4 p;
        #pragma unroll
        for (int r = 0; r < 4; ++r) {
          p[r] = (k0 + r < vl) ? __expf(acc[r] * SCALE) * inv : 0.f;
          pf[nt >> 1].e[(nt & 1) * 4 + r] = (__bf16)p[r];
        }
        *(f32x4*)(rowp + t * KT + nt * 16 + g * 4) = p;   // 16B vector attn store
      }
      // PV (swapped): ctx^T = V^T * P^T, shared per-32-key permutation {4g+j, 16+4g+j}
      #pragma unroll
      for (int kk = 0; kk < 2; ++kk)
        #pragma unroll
        for (int n8 = 0; n8 < 8; ++n8) {
          BF8 vf; vf.v = *(const bf16x8*)&sm.p2.V[cur][n8 * 16 + c][kk * 32 + g * 8];
          ctxa[n8] = __builtin_amdgcn_mfma_f32_16x16x32_bf16(vf.v, pf[kk].v, ctxa[n8], 0, 0, 0);
        }
      bar_lgkm();
    }

    // ---------------- vectorized zero-fill of fully-masked attn columns ----------------
    const int col0 = nkt * KT;   // cols >= col0 are exactly 0
    #pragma unroll 1
    for (int r = 0; r < 16; ++r) {
      float* zp = attn_out + ((size_t)bh * Qn + qb + r) * Kn;   // wave's own 16 rows
      for (int c4 = col0 + lane * 4; c4 < Kn; c4 += 256)
        *(f32x4*)(zp + c4) = (f32x4){0.f, 0.f, 0.f, 0.f};
    }

    // ---------------- epilogue: ctx[q=c][d = n8*16 + g*4 + r] ----------------
    float* cp = ctx_out + (((size_t)(b * Qn + qb + c)) * Hn + h) * Dn;
    #pragma unroll
    for (int n8 = 0; n8 < 8; ++n8)
      *(f32x4*)(cp + n8 * 16 + g * 4) = ctxa[n8];
  }
}

extern "C" void kernel_launch(void* const* d_in, const int* in_sizes, int n_in,
                              void* d_out, int out_size, void* d_ws, size_t ws_size,
                              hipStream_t stream) {
  const float* qs   = (const float*)d_in[0];
  const float* ks   = (const float*)d_in[1];
  const float* vs   = (const float*)d_in[2];
  const int*   vlen = (const int*)d_in[3];
  float* ctx  = (float*)d_out;
  float* attn = ctx + (size_t)B_ * Qn * Hn * Dn;   // outputs concatenated: ctx, attn
  attn_fwd<<<dim3((Qn / QT) * Hn), 512, 0, stream>>>(qs, ks, vs, vlen, ctx, attn);
}

// Round 11
// 223.711 us; speedup vs baseline: 1.2911x; 1.2911x over previous
//
#include <hip/hip_runtime.h>
#include <hip/hip_bf16.h>
#include <stdint.h>

#define B_ 2
#define Qn 2048
#define Kn 2048
#define Hn 16
#define Dn 128
#define QT 128     // q rows per block (8 waves x 16)
#define KT 64      // keys per tile, pass 2
#define KT1 128    // keys per tile, pass 1
#define HD (Hn*Dn)
#define KROW 132   // K row stride in shorts (264 B)
#define VROW 72    // Vt row stride in shorts (144 B)

typedef __bf16 bf16x8 __attribute__((ext_vector_type(8)));
typedef __bf16 bf16x4 __attribute__((ext_vector_type(4)));
typedef float f32x4 __attribute__((ext_vector_type(4)));

union BF8 { __bf16 e[8]; bf16x8 v; };

#define SCALE 0.088388347648318447f  // 1/sqrt(128)

struct SMp2 { unsigned short K[2][KT][KROW]; unsigned short V[2][Dn][VROW]; };
union SMu { SMp2 p2; unsigned short K1[2][KT1][KROW]; };   // 70.7 KB -> 2 blocks/CU

// lgkm-only barrier: orders LDS ops across the block WITHOUT draining vmcnt
__device__ __forceinline__ void bar_lgkm() {
  asm volatile("s_waitcnt lgkmcnt(0)" ::: "memory");
  __builtin_amdgcn_s_barrier();
  __builtin_amdgcn_sched_barrier(0);
}

__device__ __forceinline__ bf16x4 cvt4(f32x4 a) {
  bf16x4 r;
  r[0] = (__bf16)a[0]; r[1] = (__bf16)a[1];
  r[2] = (__bf16)a[2]; r[3] = (__bf16)a[3];
  return r;
}

// ---- issue-early / write-late staging (T14): loads and LDS-writes are split ----
__device__ __forceinline__ void load_k64_raw(const float* kb, int tid, f32x4* r) {
  #pragma unroll
  for (int ii = 0; ii < 4; ++ii) {
    int chunk = ii * 512 + tid;           // 64 rows x 32 chunks
    int row = chunk >> 5, cv = chunk & 31;
    r[ii] = *(const f32x4*)(kb + (size_t)row * HD + cv * 4);
  }
}
__device__ __forceinline__ void write_k64(const f32x4* r, unsigned short (*dst)[KROW], int tid) {
  #pragma unroll
  for (int ii = 0; ii < 4; ++ii) {
    int chunk = ii * 512 + tid;
    int row = chunk >> 5, cv = chunk & 31;
    *(bf16x4*)&dst[row][cv * 4] = cvt4(r[ii]);
  }
}

__device__ __forceinline__ void load_k128_raw(const float* kb, int tid, f32x4* r) {
  #pragma unroll
  for (int ii = 0; ii < 8; ++ii) {
    int chunk = ii * 512 + tid;           // 128 rows x 32 chunks
    int row = chunk >> 5, cv = chunk & 31;
    r[ii] = *(const f32x4*)(kb + (size_t)row * HD + cv * 4);
  }
}
__device__ __forceinline__ void write_k128(const f32x4* r, unsigned short (*dst)[KROW], int tid) {
  #pragma unroll
  for (int ii = 0; ii < 8; ++ii) {
    int chunk = ii * 512 + tid;
    int row = chunk >> 5, cv = chunk & 31;
    *(bf16x4*)&dst[row][cv * 4] = cvt4(r[ii]);
  }
}

// V^T: chunk (kk,gg) of row d holds keys kk*32 + {4gg..4gg+3, 16+4gg..16+4gg+3}
__device__ __forceinline__ void load_v64_raw(const float* vb, int tid, float* r) {
  int t0 = tid >> 7;
  const float* colp = vb + (tid & 127);
  #pragma unroll
  for (int rr = 0; rr < 2; ++rr) {
    int idx = rr * 4 + t0, kk = idx >> 2, gg = idx & 3;
    int kb0 = kk * 32 + gg * 4;
    #pragma unroll
    for (int j = 0; j < 4; ++j) {
      r[rr * 8 + j]     = colp[(size_t)(kb0 + j) * HD];
      r[rr * 8 + 4 + j] = colp[(size_t)(kb0 + 16 + j) * HD];
    }
  }
}
__device__ __forceinline__ void write_v64(const float* r, unsigned short (*dst)[VROW], int tid) {
  int d = tid & 127, t0 = tid >> 7;
  #pragma unroll
  for (int rr = 0; rr < 2; ++rr) {
    int idx = rr * 4 + t0, kk = idx >> 2, gg = idx & 3;
    BF8 t;
    #pragma unroll
    for (int j = 0; j < 8; ++j) t.e[j] = (__bf16)r[rr * 8 + j];
    *(bf16x8*)&dst[d][kk * 32 + gg * 8] = t.v;
  }
}

__device__ __forceinline__ void load_q(const float* qrow, BF8* qf, int g) {
  #pragma unroll
  for (int s = 0; s < 4; ++s) {
    f32x4 a0 = *(const f32x4*)(qrow + s * 32 + g * 8);
    f32x4 a1 = *(const f32x4*)(qrow + s * 32 + g * 8 + 4);
    #pragma unroll
    for (int j = 0; j < 4; ++j) { qf[s].e[j] = (__bf16)a0[j]; qf[s].e[4 + j] = (__bf16)a1[j]; }
  }
}

__global__ __launch_bounds__(512, 4) void attn_fwd(
    const float* __restrict__ qs, const float* __restrict__ ks,
    const float* __restrict__ vs, const int* __restrict__ vlen,
    float* __restrict__ ctx_out, float* __restrict__ attn_out)
{
  __shared__ __align__(16) SMu sm;

  const int tid = threadIdx.x, wave = tid >> 6, lane = tid & 63;
  const int c = lane & 15, g = lane >> 4;

  // XCD-aware decode (512 blocks, 2 blocks/CU)
  const int L   = blockIdx.x;
  const int xcd = L & 7;
  const int i5  = L >> 3;                 // 0..63
  const int bh  = ((i5 & 3) << 3) + xcd;
  const int qt  = i5 >> 2;                // 0..15
  const int b   = bh >> 4, h = bh & 15;
  const int vl  = vlen[b];
  const int qb  = qt * QT + wave * 16;

  BF8 qf[4];
  load_q(qs + (((size_t)(b * Qn + qb + c)) * Hn + h) * Dn, qf, g);
  const float* kbase = ks + ((size_t)b * Kn * Hn + h) * Dn;
  const float* vbase = vs + ((size_t)b * Kn * Hn + h) * Dn;

  // ---------------- pass 1: row sums of exp (KT1=128 tiles) ----------------
  float rs = 0.f;
  {
    const int nkt = (vl + KT1 - 1) / KT1;
    f32x4 kr[8];
    load_k128_raw(kbase, tid, kr);
    write_k128(kr, sm.K1[0], tid);
    bar_lgkm();
    for (int t = 0; t < nkt; ++t) {
      const int cur = t & 1;
      const bool pf = (t + 1 < nkt);
      if (pf) load_k128_raw(kbase + (size_t)(t + 1) * KT1 * HD, tid, kr);  // issue early
      __builtin_amdgcn_s_setprio(1);
      #pragma unroll
      for (int nt = 0; nt < 8; ++nt) {
        f32x4 acc = {0.f, 0.f, 0.f, 0.f};
        #pragma unroll
        for (int s = 0; s < 4; ++s) {
          BF8 kf; kf.v = *(const bf16x8*)&sm.K1[cur][nt * 16 + c][s * 32 + g * 8];
          acc = __builtin_amdgcn_mfma_f32_16x16x32_bf16(kf.v, qf[s].v, acc, 0, 0, 0);
        }
        const int k0 = t * KT1 + nt * 16 + g * 4;
        #pragma unroll
        for (int r = 0; r < 4; ++r)
          rs += (k0 + r < vl) ? __expf(acc[r] * SCALE) : 0.f;
      }
      __builtin_amdgcn_s_setprio(0);
      if (pf) write_k128(kr, sm.K1[cur ^ 1], tid);                          // write late
      bar_lgkm();
    }
  }
  rs += __shfl_xor(rs, 16);
  rs += __shfl_xor(rs, 32);
  const float inv = 1.0f / rs;   // row sum for q-row (qb + c)

  // ---------------- pass 2: attn writes + PV (KT=64 tiles) ----------------
  f32x4 ctxa[8];
  #pragma unroll
  for (int ii = 0; ii < 8; ++ii) ctxa[ii] = (f32x4){0.f, 0.f, 0.f, 0.f};

  const int nkt = (vl + KT - 1) / KT;
  {
    f32x4 kr[4];
    float vr[16];
    load_k64_raw(kbase, tid, kr);
    load_v64_raw(vbase, tid, vr);
    write_k64(kr, sm.p2.K[0], tid);
    write_v64(vr, sm.p2.V[0], tid);
    bar_lgkm();
    float* rowp = attn_out + ((size_t)bh * Qn + qb + c) * Kn;
    for (int t = 0; t < nkt; ++t) {
      const int cur = t & 1;
      const bool pf = (t + 1 < nkt);
      if (pf) {                                                             // issue early
        load_k64_raw(kbase + (size_t)(t + 1) * KT * HD, tid, kr);
        load_v64_raw(vbase + (size_t)(t + 1) * KT * HD, tid, vr);
      }
      __builtin_amdgcn_s_setprio(1);
      // S^T tile: lane (c,g) holds S[q=c][k = t*64 + nt*16 + g*4 + r]
      BF8 pfm[2];
      #pragma unroll
      for (int nt = 0; nt < 4; ++nt) {
        f32x4 acc = {0.f, 0.f, 0.f, 0.f};
        #pragma unroll
        for (int s = 0; s < 4; ++s) {
          BF8 kf; kf.v = *(const bf16x8*)&sm.p2.K[cur][nt * 16 + c][s * 32 + g * 8];
          acc = __builtin_amdgcn_mfma_f32_16x16x32_bf16(kf.v, qf[s].v, acc, 0, 0, 0);
        }
        const int k0 = t * KT + nt * 16 + g * 4;
        f32x4 p;
        #pragma unroll
        for (int r = 0; r < 4; ++r) {
          p[r] = (k0 + r < vl) ? __expf(acc[r] * SCALE) * inv : 0.f;
          pfm[nt >> 1].e[(nt & 1) * 4 + r] = (__bf16)p[r];
        }
        *(f32x4*)(rowp + t * KT + nt * 16 + g * 4) = p;   // 16B vector attn store
      }
      // PV (swapped): ctx^T = V^T * P^T, shared per-32-key permutation {4g+j, 16+4g+j}
      #pragma unroll
      for (int kk = 0; kk < 2; ++kk)
        #pragma unroll
        for (int n8 = 0; n8 < 8; ++n8) {
          BF8 vf; vf.v = *(const bf16x8*)&sm.p2.V[cur][n8 * 16 + c][kk * 32 + g * 8];
          ctxa[n8] = __builtin_amdgcn_mfma_f32_16x16x32_bf16(vf.v, pfm[kk].v, ctxa[n8], 0, 0, 0);
        }
      __builtin_amdgcn_s_setprio(0);
      if (pf) {                                                             // write late
        write_k64(kr, sm.p2.K[cur ^ 1], tid);
        write_v64(vr, sm.p2.V[cur ^ 1], tid);
      }
      bar_lgkm();
    }
  }

  // ---------------- vectorized zero-fill of fully-masked attn columns ----------------
  const int col0 = nkt * KT;   // cols >= col0 are exactly 0
  #pragma unroll 1
  for (int r = 0; r < 16; ++r) {
    float* zp = attn_out + ((size_t)bh * Qn + qb + r) * Kn;   // wave's own 16 rows
    for (int c4 = col0 + lane * 4; c4 < Kn; c4 += 256)
      *(f32x4*)(zp + c4) = (f32x4){0.f, 0.f, 0.f, 0.f};
  }

  // ---------------- epilogue: ctx[q=c][d = n8*16 + g*4 + r] ----------------
  float* cp = ctx_out + (((size_t)(b * Qn + qb + c)) * Hn + h) * Dn;
  #pragma unroll
  for (int n8 = 0; n8 < 8; ++n8)
    *(f32x4*)(cp + n8 * 16 + g * 4) = ctxa[n8];
}

extern "C" void kernel_launch(void* const* d_in, const int* in_sizes, int n_in,
                              void* d_out, int out_size, void* d_ws, size_t ws_size,
                              hipStream_t stream) {
  const float* qs   = (const float*)d_in[0];
  const float* ks   = (const float*)d_in[1];
  const float* vs   = (const float*)d_in[2];
  const int*   vlen = (const int*)d_in[3];
  float* ctx  = (float*)d_out;
  float* attn = ctx + (size_t)B_ * Qn * Hn * Dn;   // outputs concatenated: ctx, attn
  attn_fwd<<<dim3((Qn / QT) * B_ * Hn), 512, 0, stream>>>(qs, ks, vs, vlen, ctx, attn);
}

// Round 12
// 217.285 us; speedup vs baseline: 1.3293x; 1.0296x over previous
//
#include <hip/hip_runtime.h>
#include <hip/hip_bf16.h>
#include <stdint.h>

#define B_ 2
#define Qn 2048
#define Kn 2048
#define Hn 16
#define Dn 128
#define QT 128     // q rows per block (8 waves x 16)
#define KT 64      // keys per tile, pass 2
#define KT1 128    // keys per tile, pass 1
#define HD (Hn*Dn)
#define KROW 132   // K row stride in shorts (264 B)
#define VROW 72    // Vt row stride in shorts (144 B)

typedef __bf16 bf16x8 __attribute__((ext_vector_type(8)));
typedef __bf16 bf16x4 __attribute__((ext_vector_type(4)));
typedef float f32x4 __attribute__((ext_vector_type(4)));

union BF8 { __bf16 e[8]; bf16x8 v; };

#define SCALE 0.088388347648318447f  // 1/sqrt(128)

struct SMp2 { unsigned short K[2][KT][KROW]; unsigned short V[2][Dn][VROW]; };
union SMu { SMp2 p2; unsigned short K1[2][KT1][KROW]; };   // 70.7 KB -> 2 blocks/CU

// lgkm-only barrier: orders LDS ops across the block WITHOUT draining vmcnt
__device__ __forceinline__ void bar_lgkm() {
  asm volatile("s_waitcnt lgkmcnt(0)" ::: "memory");
  __builtin_amdgcn_s_barrier();
  __builtin_amdgcn_sched_barrier(0);
}

__device__ __forceinline__ bf16x4 cvt4(f32x4 a) {
  bf16x4 r;
  r[0] = (__bf16)a[0]; r[1] = (__bf16)a[1];
  r[2] = (__bf16)a[2]; r[3] = (__bf16)a[3];
  return r;
}

__device__ __forceinline__ void stage_k64(const float* kb, unsigned short (*dst)[KROW], int tid) {
  #pragma unroll
  for (int ii = 0; ii < 4; ++ii) {
    int chunk = ii * 512 + tid;           // 64 rows x 32 chunks
    int row = chunk >> 5, cv = chunk & 31;
    f32x4 a = *(const f32x4*)(kb + (size_t)row * HD + cv * 4);
    *(bf16x4*)&dst[row][cv * 4] = cvt4(a);
  }
}

__device__ __forceinline__ void stage_k128(const float* kb, unsigned short (*dst)[KROW], int tid) {
  #pragma unroll
  for (int ii = 0; ii < 8; ++ii) {
    int chunk = ii * 512 + tid;           // 128 rows x 32 chunks
    int row = chunk >> 5, cv = chunk & 31;
    f32x4 a = *(const f32x4*)(kb + (size_t)row * HD + cv * 4);
    *(bf16x4*)&dst[row][cv * 4] = cvt4(a);
  }
}

// V^T: chunk (kk,gg) of row d holds keys kk*32 + {4gg..4gg+3, 16+4gg..16+4gg+3}
__device__ __forceinline__ void stage_v64(const float* vb, unsigned short (*dst)[VROW], int tid) {
  int d = tid & 127, t0 = tid >> 7;       // t0 in [0,4)
  const float* colp = vb + d;
  #pragma unroll
  for (int rr = 0; rr < 2; ++rr) {
    int idx = rr * 4 + t0;                // [0,8)
    int kk = idx >> 2, gg = idx & 3;
    int kb0 = kk * 32 + gg * 4;
    BF8 t;
    #pragma unroll
    for (int j = 0; j < 4; ++j) {
      t.e[j]     = (__bf16)colp[(size_t)(kb0 + j) * HD];
      t.e[4 + j] = (__bf16)colp[(size_t)(kb0 + 16 + j) * HD];
    }
    *(bf16x8*)&dst[d][kk * 32 + gg * 8] = t.v;
  }
}

__device__ __forceinline__ void load_q(const float* qrow, BF8* qf, int g) {
  #pragma unroll
  for (int s = 0; s < 4; ++s) {
    f32x4 a0 = *(const f32x4*)(qrow + s * 32 + g * 8);
    f32x4 a1 = *(const f32x4*)(qrow + s * 32 + g * 8 + 4);
    #pragma unroll
    for (int j = 0; j < 4; ++j) { qf[s].e[j] = (__bf16)a0[j]; qf[s].e[4 + j] = (__bf16)a1[j]; }
  }
}

__global__ __launch_bounds__(512, 4) void attn_fwd(
    const float* __restrict__ qs, const float* __restrict__ ks,
    const float* __restrict__ vs, const int* __restrict__ vlen,
    float* __restrict__ ctx_out, float* __restrict__ attn_out)
{
  __shared__ __align__(16) SMu sm;

  const int tid = threadIdx.x, wave = tid >> 6, lane = tid & 63;
  const int c = lane & 15, g = lane >> 4;

  // XCD-aware decode (512 blocks, 2 blocks/CU)
  const int L   = blockIdx.x;
  const int xcd = L & 7;
  const int i5  = L >> 3;                 // 0..63
  const int bh  = ((i5 & 3) << 3) + xcd;
  const int qt  = i5 >> 2;                // 0..15
  const int b   = bh >> 4, h = bh & 15;
  const int vl  = vlen[b];
  const int qb  = qt * QT + wave * 16;

  BF8 qf[4];
  load_q(qs + (((size_t)(b * Qn + qb + c)) * Hn + h) * Dn, qf, g);
  const float* kbase = ks + ((size_t)b * Kn * Hn + h) * Dn;
  const float* vbase = vs + ((size_t)b * Kn * Hn + h) * Dn;

  // ---------------- pass 1: row sums of exp (KT1=128 tiles) ----------------
  f32x4 rsv = {0.f, 0.f, 0.f, 0.f};
  {
    const int nkt = (vl + KT1 - 1) / KT1;
    const bool hasb = (vl & (KT1 - 1)) != 0;
    stage_k128(kbase, sm.K1[0], tid);
    bar_lgkm();
    for (int t = 0; t < nkt; ++t) {
      const int cur = t & 1;
      if (t + 1 < nkt) stage_k128(kbase + (size_t)(t + 1) * KT1 * HD, sm.K1[cur ^ 1], tid);
      const bool mb = hasb && (t == nkt - 1);   // uniform per block
      #pragma unroll
      for (int nt = 0; nt < 8; ++nt) {
        f32x4 acc = {0.f, 0.f, 0.f, 0.f};
        #pragma unroll
        for (int s = 0; s < 4; ++s) {
          BF8 kf; kf.v = *(const bf16x8*)&sm.K1[cur][nt * 16 + c][s * 32 + g * 8];
          acc = __builtin_amdgcn_mfma_f32_16x16x32_bf16(kf.v, qf[s].v, acc, 0, 0, 0);
        }
        if (!mb) {
          #pragma unroll
          for (int r = 0; r < 4; ++r) rsv[r] += __expf(acc[r] * SCALE);
        } else {
          const int k0 = t * KT1 + nt * 16 + g * 4;
          #pragma unroll
          for (int r = 0; r < 4; ++r)
            rsv[r] += (k0 + r < vl) ? __expf(acc[r] * SCALE) : 0.f;
        }
      }
      bar_lgkm();
    }
  }
  float rs = (rsv[0] + rsv[1]) + (rsv[2] + rsv[3]);
  rs += __shfl_xor(rs, 16);
  rs += __shfl_xor(rs, 32);
  const float inv = 1.0f / rs;   // row sum for q-row (qb + c)

  // ---------------- pass 2: attn writes + PV pipelined one tile behind ----------------
  f32x4 ctxa[8];
  #pragma unroll
  for (int ii = 0; ii < 8; ++ii) ctxa[ii] = (f32x4){0.f, 0.f, 0.f, 0.f};

  const int nkt = (vl + KT - 1) / KT;
  const bool hasb2 = (vl & (KT - 1)) != 0;
  BF8 pprev0, pprev1;
  {
    stage_k64(kbase, sm.p2.K[0], tid);    // K0 only; V0 staged inside iter 0
    bar_lgkm();
    float* rowp = attn_out + ((size_t)bh * Qn + qb + c) * Kn;
    for (int t = 0; t < nkt; ++t) {
      const int cur = t & 1;
      if (t + 1 < nkt) stage_k64(kbase + (size_t)(t + 1) * KT * HD, sm.p2.K[cur ^ 1], tid);
      stage_v64(vbase + (size_t)t * KT * HD, sm.p2.V[cur], tid);   // V(t) -> consumed next iter
      const bool mb = hasb2 && (t == nkt - 1);

      // QK^T(t): lane (c,g) holds S[q=c][k = t*64 + nt*16 + g*4 + r]
      BF8 pc0, pc1;
      #pragma unroll
      for (int nt = 0; nt < 4; ++nt) {
        f32x4 acc = {0.f, 0.f, 0.f, 0.f};
        #pragma unroll
        for (int s = 0; s < 4; ++s) {
          BF8 kf; kf.v = *(const bf16x8*)&sm.p2.K[cur][nt * 16 + c][s * 32 + g * 8];
          acc = __builtin_amdgcn_mfma_f32_16x16x32_bf16(kf.v, qf[s].v, acc, 0, 0, 0);
        }
        f32x4 p;
        if (!mb) {
          #pragma unroll
          for (int r = 0; r < 4; ++r) p[r] = __expf(acc[r] * SCALE) * inv;
        } else {
          const int k0 = t * KT + nt * 16 + g * 4;
          #pragma unroll
          for (int r = 0; r < 4; ++r)
            p[r] = (k0 + r < vl) ? __expf(acc[r] * SCALE) * inv : 0.f;
        }
        #pragma unroll
        for (int r = 0; r < 4; ++r) {
          if (nt < 2) pc0.e[(nt & 1) * 4 + r] = (__bf16)p[r];
          else        pc1.e[(nt & 1) * 4 + r] = (__bf16)p[r];
        }
        *(f32x4*)(rowp + t * KT + nt * 16 + g * 4) = p;   // 16B vector attn store
      }

      // PV(t-1): independent chain, interleaves with the exp/store VALU above
      if (t > 0) {
        #pragma unroll
        for (int n8 = 0; n8 < 8; ++n8) {
          BF8 v0; v0.v = *(const bf16x8*)&sm.p2.V[cur ^ 1][n8 * 16 + c][g * 8];
          ctxa[n8] = __builtin_amdgcn_mfma_f32_16x16x32_bf16(v0.v, pprev0.v, ctxa[n8], 0, 0, 0);
          BF8 v1; v1.v = *(const bf16x8*)&sm.p2.V[cur ^ 1][n8 * 16 + c][32 + g * 8];
          ctxa[n8] = __builtin_amdgcn_mfma_f32_16x16x32_bf16(v1.v, pprev1.v, ctxa[n8], 0, 0, 0);
        }
      }
      pprev0 = pc0; pprev1 = pc1;
      bar_lgkm();
    }
    // drain: PV(nkt-1)
    const int lc = (nkt - 1) & 1;
    #pragma unroll
    for (int n8 = 0; n8 < 8; ++n8) {
      BF8 v0; v0.v = *(const bf16x8*)&sm.p2.V[lc][n8 * 16 + c][g * 8];
      ctxa[n8] = __builtin_amdgcn_mfma_f32_16x16x32_bf16(v0.v, pprev0.v, ctxa[n8], 0, 0, 0);
      BF8 v1; v1.v = *(const bf16x8*)&sm.p2.V[lc][n8 * 16 + c][32 + g * 8];
      ctxa[n8] = __builtin_amdgcn_mfma_f32_16x16x32_bf16(v1.v, pprev1.v, ctxa[n8], 0, 0, 0);
    }
  }

  // ---------------- vectorized zero-fill of fully-masked attn columns ----------------
  const int col0 = nkt * KT;   // cols >= col0 are exactly 0
  #pragma unroll 1
  for (int r = 0; r < 16; ++r) {
    float* zp = attn_out + ((size_t)bh * Qn + qb + r) * Kn;   // wave's own 16 rows
    for (int c4 = col0 + lane * 4; c4 < Kn; c4 += 256)
      *(f32x4*)(zp + c4) = (f32x4){0.f, 0.f, 0.f, 0.f};
  }

  // ---------------- epilogue: ctx[q=c][d = n8*16 + g*4 + r] ----------------
  float* cp = ctx_out + (((size_t)(b * Qn + qb + c)) * Hn + h) * Dn;
  #pragma unroll
  for (int n8 = 0; n8 < 8; ++n8)
    *(f32x4*)(cp + n8 * 16 + g * 4) = ctxa[n8];
}

extern "C" void kernel_launch(void* const* d_in, const int* in_sizes, int n_in,
                              void* d_out, int out_size, void* d_ws, size_t ws_size,
                              hipStream_t stream) {
  const float* qs   = (const float*)d_in[0];
  const float* ks   = (const float*)d_in[1];
  const float* vs   = (const float*)d_in[2];
  const int*   vlen = (const int*)d_in[3];
  float* ctx  = (float*)d_out;
  float* attn = ctx + (size_t)B_ * Qn * Hn * Dn;   // outputs concatenated: ctx, attn
  attn_fwd<<<dim3((Qn / QT) * B_ * Hn), 512, 0, stream>>>(qs, ks, vs, vlen, ctx, attn);
}